// Round 15
// baseline (30.510 us; speedup 1.0000x reference)
//
#include <hip/hip_runtime.h>
#include <stdint.h>

typedef _Float16 half8 __attribute__((ext_vector_type(8)));
typedef float f32x16 __attribute__((ext_vector_type(16)));

#define NPTS 8192
#define BS 4
#define TOTQ 65536            // 2*BS*NPTS (both directions)
#define TPB 256
#define NS 4                  // target slices
#define QPB 512               // queries per block (4 waves * 4 tiles * 32)
#define SLICE (NPTS / NS)     // 2048 targets per slice = 64KB of B-frags in LDS
// grid = (TOTQ/QPB=128) * NS = 512 blocks -> 2 blocks/CU (LDS 2*64KB=128 <= 160KB)

__device__ __forceinline__ float4 f4min(float4 a, float4 b) {
    return make_float4(fminf(a.x, b.x), fminf(a.y, b.y), fminf(a.z, b.z), fminf(a.w, b.w));
}

// ================= fused frag builders =================
// K=16 slot table (A,B) — verified exact R3-R14 (absmax 0.0):
//  k0-2:(-2qh_d, th_d)  k3-5:(-2ql_d, th_d)  k6-8:(-2qh_d, tl_d)
//  k9:(1,nh) k10:(1,nl) k11-13:(-2ql_d, tl_d) k14-15:(0,0)
__device__ __forceinline__ void mk_afrag(float p0, float p1, float p2,
                                         half8* ag0, half8* ag1) {
    _Float16 h0 = (_Float16)p0, h1 = (_Float16)p1, h2 = (_Float16)p2;
    _Float16 l0 = (_Float16)(p0 - (float)h0);
    _Float16 l1 = (_Float16)(p1 - (float)h1);
    _Float16 l2 = (_Float16)(p2 - (float)h2);
    _Float16 t2 = (_Float16)-2.0f;
    _Float16 m0 = t2 * h0, m1 = t2 * h1, m2 = t2 * h2;   // exact (scale by 2)
    _Float16 n0 = t2 * l0, n1 = t2 * l1, n2 = t2 * l2;
    _Float16 one = (_Float16)1.0f, zz = (_Float16)0.0f;
    *ag0 = (half8){m0, m1, m2, n0, n1, n2, m0, m1};      // k0..7
    *ag1 = (half8){m2, one, one, n0, n1, n2, zz, zz};    // k8..15
}

__device__ __forceinline__ void mk_bfrag(float p0, float p1, float p2,
                                         half8* bg0, half8* bg1) {
    float nt = p0 * p0 + p1 * p1 + p2 * p2;
    _Float16 h0 = (_Float16)p0, h1 = (_Float16)p1, h2 = (_Float16)p2;
    _Float16 l0 = (_Float16)(p0 - (float)h0);
    _Float16 l1 = (_Float16)(p1 - (float)h1);
    _Float16 l2 = (_Float16)(p2 - (float)h2);
    _Float16 nh = (_Float16)nt;
    _Float16 nl = (_Float16)(nt - (float)nh);
    _Float16 zz = (_Float16)0.0f;
    *bg0 = (half8){h0, h1, h2, h0, h1, h2, l0, l1};
    *bg1 = (half8){l2, nh, nl, l0, l1, l2, zz, zz};
}

// ================= main kernel (R12 math, barrier-free main loop) =================
// Full slice of B-frags resident in LDS (64 tiles x 1KB); ONE barrier after the
// upfront build; 256-MFMA loop runs with zero syncs -> waves free-run anti-phase.
__global__ __launch_bounds__(TPB, 2) void mfma_min_kernel(const float* __restrict__ x,
                                                          const float* __restrict__ y,
                                                          float* __restrict__ partial) {
    __shared__ __align__(16) char lds[65536];      // 64 tiles (2048 targets)
    const int tid = threadIdx.x;
    const int wave = tid >> 6;
    const int l = tid & 63;
    const int chunkid = blockIdx.x / NS;
    const int s = blockIdx.x % NS;
    const int qbase = chunkid * QPB;
    const int dir = qbase >> 15;
    const int b = (qbase >> 13) & 3;
    const int qpt = qbase & (BS * NPTS - 1);       // query point base within its set
    const int tpt = b * NPTS + s * SLICE;          // target point base within its set
    const float* qsrc = (dir == 0) ? x : y;
    const float* tsrc = (dir == 0) ? y : x;

    // ---- A fragments in-register (lane<32 holds k0-7, else k8-15) ----
    half8 afr0, afr1, afr2, afr3;
    {
        const int row = l & 31;
#define MKA(AF, a)                                                                          \
        {                                                                                   \
            const float* p = qsrc + (size_t)(qpt + (wave * 4 + (a)) * 32 + row) * 3;        \
            half8 g0, g1;                                                                   \
            mk_afrag(p[0], p[1], p[2], &g0, &g1);                                           \
            AF = (l < 32) ? g0 : g1;                                                        \
        }
        MKA(afr0, 0) MKA(afr1, 1) MKA(afr2, 2) MKA(afr3, 3)
#undef MKA
    }

    f32x16 mrun0, mrun1, mrun2, mrun3, zc;
#pragma unroll
    for (int r = 0; r < 16; ++r) {
        mrun0[r] = 3.4e38f; mrun1[r] = 3.4e38f;
        mrun2[r] = 3.4e38f; mrun3[r] = 3.4e38f;
        zc[r] = 0.0f;
    }

    // ---- B build: 8 targets/thread, 2-deep load/pack pipeline, ONE barrier ----
#define BLOADs(c, RA, RB, RC)                                                               \
    {                                                                                       \
        const float2* p = (const float2*)(tsrc + (size_t)(tpt + (c) * 512 + tid * 2) * 3);  \
        RA = p[0]; RB = p[1]; RC = p[2];                                                    \
    }
    // LDS layout: [tile(64)][kg(2)][row(32)][8 f16]  (1KB per tile)
#define BPACKs(c, RA, RB, RC)                                                               \
    {                                                                                       \
        const int t0 = (c) * 512 + tid * 2;                                                 \
        const int base = (t0 >> 5) * 1024;                                                  \
        const int r0 = (t0 & 31) * 16;                                                      \
        half8 g0, g1;                                                                       \
        mk_bfrag(RA.x, RA.y, RB.x, &g0, &g1);                                               \
        *(half8*)(&lds[base + r0]) = g0;                                                    \
        *(half8*)(&lds[base + 512 + r0]) = g1;                                              \
        mk_bfrag(RB.y, RC.x, RC.y, &g0, &g1);                                               \
        *(half8*)(&lds[base + r0 + 16]) = g0;                                               \
        *(half8*)(&lds[base + 512 + r0 + 16]) = g1;                                         \
    }
    {
        float2 rA0, rB0, rC0, rA1, rB1, rC1;
        BLOADs(0, rA0, rB0, rC0)
        BLOADs(1, rA1, rB1, rC1)
        BPACKs(0, rA0, rB0, rC0)
        BLOADs(2, rA0, rB0, rC0)
        BPACKs(1, rA1, rB1, rC1)
        BLOADs(3, rA1, rB1, rC1)
        BPACKs(2, rA0, rB0, rC0)
        BPACKs(3, rA1, rB1, rC1)
    }
    __syncthreads();            // the ONLY pre-epilogue barrier

    // one a-group: 2 MFMA + 16 v_min3 (R12-proven core)
#define AGROUP(AF, MR, BB0, BB1)                                                            \
    {                                                                                       \
        f32x16 d0 = __builtin_amdgcn_mfma_f32_32x32x16_f16(AF, BB0, zc, 0, 0, 0);           \
        f32x16 d1 = __builtin_amdgcn_mfma_f32_32x32x16_f16(AF, BB1, zc, 0, 0, 0);           \
        _Pragma("unroll")                                                                   \
        for (int r = 0; r < 16; ++r)                                                        \
            MR[r] = fminf(fminf(MR[r], d0[r]), d1[r]);  /* v_min3 */                        \
    }

#define COMPUTE(BB0, BB1)                                                                   \
    AGROUP(afr0, mrun0, BB0, BB1)                                                           \
    AGROUP(afr1, mrun1, BB0, BB1)                                                           \
    AGROUP(afr2, mrun2, BB0, BB1)                                                           \
    AGROUP(afr3, mrun3, BB0, BB1)

    {
        const char* B = lds;
        // ping-pong tile-pair registers: no copy movs; 32 pairs (64 tiles), no syncs
        half8 bA0 = *(const half8*)(B + l * 16);
        half8 bA1 = *(const half8*)(B + 1024 + l * 16);
        half8 bB0, bB1;
#pragma unroll 1
        for (int p = 0; p < 32; p += 2) {
            bB0 = *(const half8*)(B + (p + 1) * 2048 + l * 16);
            bB1 = *(const half8*)(B + (p + 1) * 2048 + 1024 + l * 16);
            COMPUTE(bA0, bA1);
            int pn = (p + 2) & 31;  // wraps on last iter: harmless re-read of pair 0
            bA0 = *(const half8*)(B + pn * 2048 + l * 16);
            bA1 = *(const half8*)(B + pn * 2048 + 1024 + l * 16);
            COMPUTE(bB0, bB1);
        }
    }
#undef BLOADs
#undef BPACKs
#undef COMPUTE
#undef AGROUP

    // ===== epilogue: column-min via LDS transpose (R8-proven; reuses lds) =====
    // D row = (reg&3) + 8*(reg>>2) + 4*(lane>>5), col = lane&31  [verified R3-R14]
    __syncthreads();            // all waves done reading B from lds
    float* ep = (float*)(&lds[0]);      // 4 waves * 32 rows * 36 floats = 18432B
    const int hi4 = (l >> 5) * 4;
    const int col = l & 31;

#define EPASS(AA, MR)                                                                       \
    {                                                                                       \
        _Pragma("unroll")                                                                   \
        for (int r = 0; r < 16; ++r) {                                                      \
            int row = (r & 3) + 8 * (r >> 2) + hi4;                                         \
            ep[wave * 1152 + row * 36 + col] = MR[r];                                       \
        }                                                                                   \
    }                                                                                       \
    __syncthreads();                                                                        \
    if (tid < 128) {                                                                        \
        const float4* rp = (const float4*)(ep + (tid >> 5) * 1152 + (tid & 31) * 36);       \
        float4 a01 = f4min(rp[0], rp[1]), a23 = f4min(rp[2], rp[3]);                        \
        float4 a45 = f4min(rp[4], rp[5]), a67 = f4min(rp[6], rp[7]);                        \
        float4 t = f4min(f4min(a01, a23), f4min(a45, a67));                                 \
        float m = fminf(fminf(t.x, t.y), fminf(t.z, t.w));                                  \
        partial[(size_t)s * TOTQ + qbase + (tid >> 5) * 128 + (AA) * 32 + (tid & 31)] = m;  \
    }                                                                                       \
    __syncthreads();

    EPASS(0, mrun0)
    EPASS(1, mrun1)
    EPASS(2, mrun2)
    EPASS(3, mrun3)
#undef EPASS
}

// combine: min over slices + inline ||q||^2 from raw points + sqrt + block tree-sum
__global__ __launch_bounds__(TPB) void combine_mfma_kernel(const float* __restrict__ partial,
                                                           const float* __restrict__ x,
                                                           const float* __restrict__ y,
                                                           float* __restrict__ bsum) {
    int q = blockIdx.x * TPB + threadIdx.x;
    int dir = q >> 15;
    int pidx = q & (BS * NPTS - 1);
    const float* src = (dir == 0) ? x : y;
    float p0 = src[pidx * 3 + 0], p1 = src[pidx * 3 + 1], p2 = src[pidx * 3 + 2];
    float nq = p0 * p0 + p1 * p1 + p2 * p2;   // bitwise == reference pack

    float m = partial[q];
#pragma unroll
    for (int s = 1; s < NS; ++s)
        m = fminf(m, partial[(size_t)s * TOTQ + q]);
    float d = sqrtf(fmaxf(m + nq, 0.0f));
    __shared__ float red[TPB];
    red[threadIdx.x] = d;
    __syncthreads();
    for (int off = TPB / 2; off > 0; off >>= 1) {
        if (threadIdx.x < off) red[threadIdx.x] += red[threadIdx.x + off];
        __syncthreads();
    }
    if (threadIdx.x == 0) bsum[blockIdx.x] = red[0];
}

__global__ __launch_bounds__(TPB) void final_kernel(const float* __restrict__ bsum,
                                                    float* __restrict__ out) {
    __shared__ float red[TPB];
    red[threadIdx.x] = bsum[threadIdx.x];
    __syncthreads();
    for (int off = TPB / 2; off > 0; off >>= 1) {
        if (threadIdx.x < off) red[threadIdx.x] += red[threadIdx.x + off];
        __syncthreads();
    }
    if (threadIdx.x == 0) out[0] = red[0] * (1.0f / 32768.0f);
}

// ================= VALU fallback (round-2 proven) =================
#define QPT 8
#define QPBF (TPB * QPT)
#define NGROUP (TOTQ / QPBF)
#define FNS 8

__global__ __launch_bounds__(TPB) void pack_kernel(const float* __restrict__ x,
                                                   const float* __restrict__ y,
                                                   float4* __restrict__ px,
                                                   float4* __restrict__ py) {
    int i = blockIdx.x * TPB + threadIdx.x;
    if (i < BS * NPTS) {
        float x0 = x[i * 3 + 0], x1 = x[i * 3 + 1], x2 = x[i * 3 + 2];
        px[i] = make_float4(x0, x1, x2, x0 * x0 + x1 * x1 + x2 * x2);
        float y0 = y[i * 3 + 0], y1 = y[i * 3 + 1], y2 = y[i * 3 + 2];
        py[i] = make_float4(y0, y1, y2, y0 * y0 + y1 * y1 + y2 * y2);
    }
}

__global__ __launch_bounds__(TPB) void chamfer_min_kernel(const float4* __restrict__ px,
                                                          const float4* __restrict__ py,
                                                          float* __restrict__ partial) {
    constexpr int SLICEF = NPTS / FNS;
    __shared__ float4 tile[SLICEF];
    const int t = threadIdx.x;
    const int g = blockIdx.x / FNS;
    const int s = blockIdx.x % FNS;
    const int dir = g >> 4;
    const int b = (g >> 2) & 3;
    const int chunk = g & 3;
    const float4* q  = (dir == 0 ? px : py) + b * NPTS + chunk * QPBF;
    const float4* tg = (dir == 0 ? py : px) + b * NPTS + s * SLICEF;
    float a0[QPT], a1[QPT], a2[QPT], qq[QPT], mv[QPT];
#pragma unroll
    for (int i = 0; i < QPT; ++i) {
        float4 v = q[i * TPB + t];
        a0[i] = -2.0f * v.x; a1[i] = -2.0f * v.y; a2[i] = -2.0f * v.z;
        qq[i] = v.w; mv[i] = 3.4e38f;
    }
#pragma unroll
    for (int i = 0; i < SLICEF / TPB; ++i)
        tile[i * TPB + t] = tg[i * TPB + t];
    __syncthreads();
#pragma unroll 2
    for (int j = 0; j < SLICEF; j += 2) {
        float4 v0 = tile[j], v1 = tile[j + 1];
#pragma unroll
        for (int i = 0; i < QPT; ++i) {
            float d0 = fmaf(a2[i], v0.z, fmaf(a1[i], v0.y, fmaf(a0[i], v0.x, v0.w)));
            float d1 = fmaf(a2[i], v1.z, fmaf(a1[i], v1.y, fmaf(a0[i], v1.x, v1.w)));
            mv[i] = fminf(fminf(mv[i], d0), d1);
        }
    }
    const int qg0 = g * QPBF;
#pragma unroll
    for (int i = 0; i < QPT; ++i)
        partial[(size_t)s * TOTQ + qg0 + i * TPB + t] = mv[i] + qq[i];
}

__global__ __launch_bounds__(TPB) void combine_kernel(const float* __restrict__ partial,
                                                      float* __restrict__ bsum) {
    int idx = blockIdx.x * TPB + threadIdx.x;
    float m = 3.4e38f;
#pragma unroll
    for (int s = 0; s < FNS; ++s)
        m = fminf(m, partial[(size_t)s * TOTQ + idx]);
    float d = sqrtf(fmaxf(m, 0.0f));
    __shared__ float red[TPB];
    red[threadIdx.x] = d;
    __syncthreads();
    for (int off = TPB / 2; off > 0; off >>= 1) {
        if (threadIdx.x < off) red[threadIdx.x] += red[threadIdx.x + off];
        __syncthreads();
    }
    if (threadIdx.x == 0) bsum[blockIdx.x] = red[0];
}

// ================= launch =================
extern "C" void kernel_launch(void* const* d_in, const int* in_sizes, int n_in,
                              void* d_out, int out_size, void* d_ws, size_t ws_size,
                              hipStream_t stream) {
    const float* x = (const float*)d_in[0];
    const float* y = (const float*)d_in[1];
    float* out = (float*)d_out;
    char* ws = (char*)d_ws;

    // MFMA-path ws: partial NS*256KB | bsum 1KB
    const size_t off_bs = (size_t)NS * TOTQ * 4;
    const size_t need = off_bs + 1024;

    if (ws_size >= need) {
        float* partial = (float*)ws;
        float* bsum = (float*)(ws + off_bs);
        hipLaunchKernelGGL(mfma_min_kernel, dim3((TOTQ / QPB) * NS), dim3(TPB), 0, stream,
                           x, y, partial);
        hipLaunchKernelGGL(combine_mfma_kernel, dim3(TOTQ / TPB), dim3(TPB), 0, stream,
                           partial, x, y, bsum);
        hipLaunchKernelGGL(final_kernel, dim3(1), dim3(TPB), 0, stream, bsum, out);
    } else {
        float4* px = (float4*)ws;
        float4* py = (float4*)(ws + 512 * 1024);
        float* partial = (float*)(ws + 1024 * 1024);
        float* bsum = (float*)(ws + 1024 * 1024 + (size_t)FNS * TOTQ * 4);
        hipLaunchKernelGGL(pack_kernel, dim3((BS * NPTS + TPB - 1) / TPB), dim3(TPB), 0, stream,
                           x, y, px, py);
        hipLaunchKernelGGL(chamfer_min_kernel, dim3(NGROUP * FNS), dim3(TPB), 0, stream,
                           px, py, partial);
        hipLaunchKernelGGL(combine_kernel, dim3(TOTQ / TPB), dim3(TPB), 0, stream,
                           partial, bsum);
        hipLaunchKernelGGL(final_kernel, dim3(1), dim3(TPB), 0, stream, bsum, out);
    }
}

// Round 16
// 29.642 us; speedup vs baseline: 1.0293x; 1.0293x over previous
//
#include <hip/hip_runtime.h>
#include <stdint.h>

typedef _Float16 half8 __attribute__((ext_vector_type(8)));
typedef float f32x16 __attribute__((ext_vector_type(16)));

#define NPTS 8192
#define BS 4
#define TOTQ 65536            // 2*BS*NPTS (both directions)
#define TPB 256
#define NS 4                  // target slices
#define QPB 512               // queries per block (4 waves * 4 tiles * 32)
#define NCHUNK 4              // SLICE/512 chunks per slice
#define SLICE (NPTS / NS)     // 2048 targets per slice
// grid = (TOTQ/QPB=128) * NS = 512 blocks -> 2 blocks/CU

__device__ __forceinline__ float4 f4min(float4 a, float4 b) {
    return make_float4(fminf(a.x, b.x), fminf(a.y, b.y), fminf(a.z, b.z), fminf(a.w, b.w));
}

// ================= fused frag builders =================
// K=16 slot table (A,B) — verified exact R3-R15 (absmax 0.0):
//  k0-2:(-2qh_d, th_d)  k3-5:(-2ql_d, th_d)  k6-8:(-2qh_d, tl_d)
//  k9:(1,nh) k10:(1,nl) k11-13:(-2ql_d, tl_d) k14-15:(0,0)
__device__ __forceinline__ void mk_afrag(float p0, float p1, float p2,
                                         half8* ag0, half8* ag1) {
    _Float16 h0 = (_Float16)p0, h1 = (_Float16)p1, h2 = (_Float16)p2;
    _Float16 l0 = (_Float16)(p0 - (float)h0);
    _Float16 l1 = (_Float16)(p1 - (float)h1);
    _Float16 l2 = (_Float16)(p2 - (float)h2);
    _Float16 t2 = (_Float16)-2.0f;
    _Float16 m0 = t2 * h0, m1 = t2 * h1, m2 = t2 * h2;   // exact (scale by 2)
    _Float16 n0 = t2 * l0, n1 = t2 * l1, n2 = t2 * l2;
    _Float16 one = (_Float16)1.0f, zz = (_Float16)0.0f;
    *ag0 = (half8){m0, m1, m2, n0, n1, n2, m0, m1};      // k0..7
    *ag1 = (half8){m2, one, one, n0, n1, n2, zz, zz};    // k8..15
}

__device__ __forceinline__ void mk_bfrag(float p0, float p1, float p2,
                                         half8* bg0, half8* bg1) {
    float nt = p0 * p0 + p1 * p1 + p2 * p2;
    _Float16 h0 = (_Float16)p0, h1 = (_Float16)p1, h2 = (_Float16)p2;
    _Float16 l0 = (_Float16)(p0 - (float)h0);
    _Float16 l1 = (_Float16)(p1 - (float)h1);
    _Float16 l2 = (_Float16)(p2 - (float)h2);
    _Float16 nh = (_Float16)nt;
    _Float16 nl = (_Float16)(nt - (float)nh);
    _Float16 zz = (_Float16)0.0f;
    *bg0 = (half8){h0, h1, h2, h0, h1, h2, l0, l1};
    *bg1 = (half8){l2, nh, nl, l0, l1, l2, zz, zz};
}

// ================= fused main kernel (R12 structure, single-d fold) =================
__global__ __launch_bounds__(TPB, 2) void mfma_min_kernel(const float* __restrict__ x,
                                                          const float* __restrict__ y,
                                                          float* __restrict__ partial) {
    __shared__ __align__(16) char lds[2][16384];   // 16 tiles (512 targets) per buf
    const int tid = threadIdx.x;
    const int wave = tid >> 6;
    const int l = tid & 63;
    const int chunkid = blockIdx.x / NS;
    const int s = blockIdx.x % NS;
    const int qbase = chunkid * QPB;
    const int dir = qbase >> 15;
    const int b = (qbase >> 13) & 3;
    const int qpt = qbase & (BS * NPTS - 1);       // query point base within its set
    const int tpt = b * NPTS + s * SLICE;          // target point base within its set
    const float* qsrc = (dir == 0) ? x : y;
    const float* tsrc = (dir == 0) ? y : x;

    // ---- A fragments in-register (lane<32 holds k0-7, else k8-15) ----
    half8 afr0, afr1, afr2, afr3;
    {
        const int row = l & 31;
#define MKA(AF, a)                                                                          \
        {                                                                                   \
            const float* p = qsrc + (size_t)(qpt + (wave * 4 + (a)) * 32 + row) * 3;        \
            half8 g0, g1;                                                                   \
            mk_afrag(p[0], p[1], p[2], &g0, &g1);                                           \
            AF = (l < 32) ? g0 : g1;                                                        \
        }
        MKA(afr0, 0) MKA(afr1, 1) MKA(afr2, 2) MKA(afr3, 3)
#undef MKA
    }

    f32x16 mrun0, mrun1, mrun2, mrun3, zc;
#pragma unroll
    for (int r = 0; r < 16; ++r) {
        mrun0[r] = 3.4e38f; mrun1[r] = 3.4e38f;
        mrun2[r] = 3.4e38f; mrun3[r] = 3.4e38f;
        zc[r] = 0.0f;
    }

    // ---- B staging: raw->reg (issue early), pack->ds_write (late) ----
    float2 rA, rB, rC;   // 2 targets (24B) per thread
#define BLOAD(c)                                                                            \
    {                                                                                       \
        const float2* p = (const float2*)(tsrc + (size_t)(tpt + (c) * 512 + tid * 2) * 3);  \
        rA = p[0]; rB = p[1]; rC = p[2];                                                    \
    }
#define BPACK(buf)                                                                          \
    {                                                                                       \
        const int t0 = tid * 2;                                                             \
        const int base = (t0 >> 5) * 1024;                                                  \
        const int r0 = (t0 & 31) * 16;                                                      \
        half8 g0, g1;                                                                       \
        mk_bfrag(rA.x, rA.y, rB.x, &g0, &g1);                                               \
        *(half8*)(&lds[buf][base + r0]) = g0;                                               \
        *(half8*)(&lds[buf][base + 512 + r0]) = g1;                                         \
        mk_bfrag(rB.y, rC.x, rC.y, &g0, &g1);                                               \
        *(half8*)(&lds[buf][base + r0 + 16]) = g0;                                          \
        *(half8*)(&lds[buf][base + 512 + r0 + 16]) = g1;                                    \
    }

    // R16 single variable: immediate per-MFMA fold. One 16-reg d per chain; 4
    // independent chains per fenced region -> compiler round-robins MFMA issue
    // and folds each chain after its latency has elapsed under later MFMAs.
#define AGROUP1(AF, MR, BB)                                                                 \
    {                                                                                       \
        f32x16 d = __builtin_amdgcn_mfma_f32_32x32x16_f16(AF, BB, zc, 0, 0, 0);             \
        _Pragma("unroll")                                                                   \
        for (int r = 0; r < 16; ++r)                                                        \
            MR[r] = fminf(MR[r], d[r]);  /* v_min */                                        \
    }

#define COMPUTE(BB0, BB1)                                                                   \
    AGROUP1(afr0, mrun0, BB0)                                                               \
    AGROUP1(afr1, mrun1, BB0)                                                               \
    AGROUP1(afr2, mrun2, BB0)                                                               \
    AGROUP1(afr3, mrun3, BB0)                                                               \
    __builtin_amdgcn_sched_barrier(0);                                                      \
    AGROUP1(afr0, mrun0, BB1)                                                               \
    AGROUP1(afr1, mrun1, BB1)                                                               \
    AGROUP1(afr2, mrun2, BB1)                                                               \
    AGROUP1(afr3, mrun3, BB1)                                                               \
    __builtin_amdgcn_sched_barrier(0);

    BLOAD(0)
    BPACK(0)
    __syncthreads();           // buf0 fully written

    int cur = 0;
#pragma unroll 1
    for (int c = 0; c < NCHUNK; ++c) {
        if (c + 1 < NCHUNK) BLOAD(c + 1)   // issue raw loads; latency hides under COMPUTE
        const char* B = lds[cur];
        half8 bA0 = *(const half8*)(B + l * 16);
        half8 bA1 = *(const half8*)(B + 1024 + l * 16);
        half8 bB0, bB1;
#pragma unroll 1
        for (int p = 0; p < 8; p += 2) {
            bB0 = *(const half8*)(B + (p + 1) * 2048 + l * 16);
            bB1 = *(const half8*)(B + (p + 1) * 2048 + 1024 + l * 16);
            COMPUTE(bA0, bA1);
            int pn = (p + 2) & 7;   // wraps on last iter: harmless re-read of pair 0
            bA0 = *(const half8*)(B + pn * 2048 + l * 16);
            bA1 = *(const half8*)(B + pn * 2048 + 1024 + l * 16);
            COMPUTE(bB0, bB1);
        }
        if (c + 1 < NCHUNK) {
            BPACK(cur ^ 1)
            __syncthreads();    // writes visible AND all waves done with lds[cur]
            cur ^= 1;
        }
    }
#undef BLOAD
#undef BPACK
#undef COMPUTE
#undef AGROUP1

    // ===== epilogue: column-min via LDS transpose (R8-proven) =====
    // D row = (reg&3) + 8*(reg>>2) + 4*(lane>>5), col = lane&31  [verified R3-R15]
    __syncthreads();            // all waves done reading lds[cur]
    float* ep = (float*)(&lds[0][0]);   // 4 waves * 32 rows * 36 floats = 18432B
    const int hi4 = (l >> 5) * 4;
    const int col = l & 31;

#define EPASS(AA, MR)                                                                       \
    {                                                                                       \
        _Pragma("unroll")                                                                   \
        for (int r = 0; r < 16; ++r) {                                                      \
            int row = (r & 3) + 8 * (r >> 2) + hi4;                                         \
            ep[wave * 1152 + row * 36 + col] = MR[r];                                       \
        }                                                                                   \
    }                                                                                       \
    __syncthreads();                                                                        \
    if (tid < 128) {                                                                        \
        const float4* rp = (const float4*)(ep + (tid >> 5) * 1152 + (tid & 31) * 36);       \
        float4 a01 = f4min(rp[0], rp[1]), a23 = f4min(rp[2], rp[3]);                        \
        float4 a45 = f4min(rp[4], rp[5]), a67 = f4min(rp[6], rp[7]);                        \
        float4 t = f4min(f4min(a01, a23), f4min(a45, a67));                                 \
        float m = fminf(fminf(t.x, t.y), fminf(t.z, t.w));                                  \
        partial[(size_t)s * TOTQ + qbase + (tid >> 5) * 128 + (AA) * 32 + (tid & 31)] = m;  \
    }                                                                                       \
    __syncthreads();

    EPASS(0, mrun0)
    EPASS(1, mrun1)
    EPASS(2, mrun2)
    EPASS(3, mrun3)
#undef EPASS
}

// combine: min over slices + inline ||q||^2 from raw points + sqrt + block tree-sum
__global__ __launch_bounds__(TPB) void combine_mfma_kernel(const float* __restrict__ partial,
                                                           const float* __restrict__ x,
                                                           const float* __restrict__ y,
                                                           float* __restrict__ bsum) {
    int q = blockIdx.x * TPB + threadIdx.x;
    int dir = q >> 15;
    int pidx = q & (BS * NPTS - 1);
    const float* src = (dir == 0) ? x : y;
    float p0 = src[pidx * 3 + 0], p1 = src[pidx * 3 + 1], p2 = src[pidx * 3 + 2];
    float nq = p0 * p0 + p1 * p1 + p2 * p2;   // bitwise == reference pack

    float m = partial[q];
#pragma unroll
    for (int s = 1; s < NS; ++s)
        m = fminf(m, partial[(size_t)s * TOTQ + q]);
    float d = sqrtf(fmaxf(m + nq, 0.0f));
    __shared__ float red[TPB];
    red[threadIdx.x] = d;
    __syncthreads();
    for (int off = TPB / 2; off > 0; off >>= 1) {
        if (threadIdx.x < off) red[threadIdx.x] += red[threadIdx.x + off];
        __syncthreads();
    }
    if (threadIdx.x == 0) bsum[blockIdx.x] = red[0];
}

__global__ __launch_bounds__(TPB) void final_kernel(const float* __restrict__ bsum,
                                                    float* __restrict__ out) {
    __shared__ float red[TPB];
    red[threadIdx.x] = bsum[threadIdx.x];
    __syncthreads();
    for (int off = TPB / 2; off > 0; off >>= 1) {
        if (threadIdx.x < off) red[threadIdx.x] += red[threadIdx.x + off];
        __syncthreads();
    }
    if (threadIdx.x == 0) out[0] = red[0] * (1.0f / 32768.0f);
}

// ================= VALU fallback (round-2 proven) =================
#define QPT 8
#define QPBF (TPB * QPT)
#define NGROUP (TOTQ / QPBF)
#define FNS 8

__global__ __launch_bounds__(TPB) void pack_kernel(const float* __restrict__ x,
                                                   const float* __restrict__ y,
                                                   float4* __restrict__ px,
                                                   float4* __restrict__ py) {
    int i = blockIdx.x * TPB + threadIdx.x;
    if (i < BS * NPTS) {
        float x0 = x[i * 3 + 0], x1 = x[i * 3 + 1], x2 = x[i * 3 + 2];
        px[i] = make_float4(x0, x1, x2, x0 * x0 + x1 * x1 + x2 * x2);
        float y0 = y[i * 3 + 0], y1 = y[i * 3 + 1], y2 = y[i * 3 + 2];
        py[i] = make_float4(y0, y1, y2, y0 * y0 + y1 * y1 + y2 * y2);
    }
}

__global__ __launch_bounds__(TPB) void chamfer_min_kernel(const float4* __restrict__ px,
                                                          const float4* __restrict__ py,
                                                          float* __restrict__ partial) {
    constexpr int SLICEF = NPTS / FNS;
    __shared__ float4 tile[SLICEF];
    const int t = threadIdx.x;
    const int g = blockIdx.x / FNS;
    const int s = blockIdx.x % FNS;
    const int dir = g >> 4;
    const int b = (g >> 2) & 3;
    const int chunk = g & 3;
    const float4* q  = (dir == 0 ? px : py) + b * NPTS + chunk * QPBF;
    const float4* tg = (dir == 0 ? py : px) + b * NPTS + s * SLICEF;
    float a0[QPT], a1[QPT], a2[QPT], qq[QPT], mv[QPT];
#pragma unroll
    for (int i = 0; i < QPT; ++i) {
        float4 v = q[i * TPB + t];
        a0[i] = -2.0f * v.x; a1[i] = -2.0f * v.y; a2[i] = -2.0f * v.z;
        qq[i] = v.w; mv[i] = 3.4e38f;
    }
#pragma unroll
    for (int i = 0; i < SLICEF / TPB; ++i)
        tile[i * TPB + t] = tg[i * TPB + t];
    __syncthreads();
#pragma unroll 2
    for (int j = 0; j < SLICEF; j += 2) {
        float4 v0 = tile[j], v1 = tile[j + 1];
#pragma unroll
        for (int i = 0; i < QPT; ++i) {
            float d0 = fmaf(a2[i], v0.z, fmaf(a1[i], v0.y, fmaf(a0[i], v0.x, v0.w)));
            float d1 = fmaf(a2[i], v1.z, fmaf(a1[i], v1.y, fmaf(a0[i], v1.x, v1.w)));
            mv[i] = fminf(fminf(mv[i], d0), d1);
        }
    }
    const int qg0 = g * QPBF;
#pragma unroll
    for (int i = 0; i < QPT; ++i)
        partial[(size_t)s * TOTQ + qg0 + i * TPB + t] = mv[i] + qq[i];
}

__global__ __launch_bounds__(TPB) void combine_kernel(const float* __restrict__ partial,
                                                      float* __restrict__ bsum) {
    int idx = blockIdx.x * TPB + threadIdx.x;
    float m = 3.4e38f;
#pragma unroll
    for (int s = 0; s < FNS; ++s)
        m = fminf(m, partial[(size_t)s * TOTQ + idx]);
    float d = sqrtf(fmaxf(m, 0.0f));
    __shared__ float red[TPB];
    red[threadIdx.x] = d;
    __syncthreads();
    for (int off = TPB / 2; off > 0; off >>= 1) {
        if (threadIdx.x < off) red[threadIdx.x] += red[threadIdx.x + off];
        __syncthreads();
    }
    if (threadIdx.x == 0) bsum[blockIdx.x] = red[0];
}

// ================= launch =================
extern "C" void kernel_launch(void* const* d_in, const int* in_sizes, int n_in,
                              void* d_out, int out_size, void* d_ws, size_t ws_size,
                              hipStream_t stream) {
    const float* x = (const float*)d_in[0];
    const float* y = (const float*)d_in[1];
    float* out = (float*)d_out;
    char* ws = (char*)d_ws;

    // MFMA-path ws: partial NS*256KB | bsum 1KB
    const size_t off_bs = (size_t)NS * TOTQ * 4;
    const size_t need = off_bs + 1024;

    if (ws_size >= need) {
        float* partial = (float*)ws;
        float* bsum = (float*)(ws + off_bs);
        hipLaunchKernelGGL(mfma_min_kernel, dim3((TOTQ / QPB) * NS), dim3(TPB), 0, stream,
                           x, y, partial);
        hipLaunchKernelGGL(combine_mfma_kernel, dim3(TOTQ / TPB), dim3(TPB), 0, stream,
                           partial, x, y, bsum);
        hipLaunchKernelGGL(final_kernel, dim3(1), dim3(TPB), 0, stream, bsum, out);
    } else {
        float4* px = (float4*)ws;
        float4* py = (float4*)(ws + 512 * 1024);
        float* partial = (float*)(ws + 1024 * 1024);
        float* bsum = (float*)(ws + 1024 * 1024 + (size_t)FNS * TOTQ * 4);
        hipLaunchKernelGGL(pack_kernel, dim3((BS * NPTS + TPB - 1) / TPB), dim3(TPB), 0, stream,
                           x, y, px, py);
        hipLaunchKernelGGL(chamfer_min_kernel, dim3(NGROUP * FNS), dim3(TPB), 0, stream,
                           px, py, partial);
        hipLaunchKernelGGL(combine_kernel, dim3(TOTQ / TPB), dim3(TPB), 0, stream,
                           partial, bsum);
        hipLaunchKernelGGL(final_kernel, dim3(1), dim3(TPB), 0, stream, bsum, out);
    }
}

// Round 17
// 28.871 us; speedup vs baseline: 1.0568x; 1.0267x over previous
//
#include <hip/hip_runtime.h>
#include <stdint.h>

typedef _Float16 half8 __attribute__((ext_vector_type(8)));
typedef float f32x16 __attribute__((ext_vector_type(16)));

#define NPTS 8192
#define BS 4
#define TOTQ 65536            // 2*BS*NPTS (both directions)
#define TPB 256
#define NS 4                  // target slices
#define QPB 512               // queries per block (4 waves * 4 tiles * 32)
#define NCHUNK 4              // SLICE/512 chunks per slice
#define SLICE (NPTS / NS)     // 2048 targets per slice
// grid = (TOTQ/QPB=128) * NS = 512 blocks -> 2 blocks/CU

__device__ __forceinline__ float4 f4min(float4 a, float4 b) {
    return make_float4(fminf(a.x, b.x), fminf(a.y, b.y), fminf(a.z, b.z), fminf(a.w, b.w));
}

// ================= fused frag builders =================
// K=16 slot table (A,B) — verified exact R3-R16 (absmax 0.0):
//  k0-2:(-2qh_d, th_d)  k3-5:(-2ql_d, th_d)  k6-8:(-2qh_d, tl_d)
//  k9:(1,nh) k10:(1,nl) k11-13:(-2ql_d, tl_d) k14-15:(0,0)
__device__ __forceinline__ void mk_afrag(float p0, float p1, float p2,
                                         half8* ag0, half8* ag1) {
    _Float16 h0 = (_Float16)p0, h1 = (_Float16)p1, h2 = (_Float16)p2;
    _Float16 l0 = (_Float16)(p0 - (float)h0);
    _Float16 l1 = (_Float16)(p1 - (float)h1);
    _Float16 l2 = (_Float16)(p2 - (float)h2);
    _Float16 t2 = (_Float16)-2.0f;
    _Float16 m0 = t2 * h0, m1 = t2 * h1, m2 = t2 * h2;   // exact (scale by 2)
    _Float16 n0 = t2 * l0, n1 = t2 * l1, n2 = t2 * l2;
    _Float16 one = (_Float16)1.0f, zz = (_Float16)0.0f;
    *ag0 = (half8){m0, m1, m2, n0, n1, n2, m0, m1};      // k0..7
    *ag1 = (half8){m2, one, one, n0, n1, n2, zz, zz};    // k8..15
}

__device__ __forceinline__ void mk_bfrag(float p0, float p1, float p2,
                                         half8* bg0, half8* bg1) {
    float nt = p0 * p0 + p1 * p1 + p2 * p2;
    _Float16 h0 = (_Float16)p0, h1 = (_Float16)p1, h2 = (_Float16)p2;
    _Float16 l0 = (_Float16)(p0 - (float)h0);
    _Float16 l1 = (_Float16)(p1 - (float)h1);
    _Float16 l2 = (_Float16)(p2 - (float)h2);
    _Float16 nh = (_Float16)nt;
    _Float16 nl = (_Float16)(nt - (float)nh);
    _Float16 zz = (_Float16)0.0f;
    *bg0 = (half8){h0, h1, h2, h0, h1, h2, l0, l1};
    *bg1 = (half8){l2, nh, nl, l0, l1, l2, zz, zz};
}

// ================= fused main kernel (R12 final) =================
__global__ __launch_bounds__(TPB, 2) void mfma_min_kernel(const float* __restrict__ x,
                                                          const float* __restrict__ y,
                                                          float* __restrict__ partial) {
    __shared__ __align__(16) char lds[2][16384];   // 16 tiles (512 targets) per buf
    const int tid = threadIdx.x;
    const int wave = tid >> 6;
    const int l = tid & 63;
    const int chunkid = blockIdx.x / NS;
    const int s = blockIdx.x % NS;
    const int qbase = chunkid * QPB;
    const int dir = qbase >> 15;
    const int b = (qbase >> 13) & 3;
    const int qpt = qbase & (BS * NPTS - 1);       // query point base within its set
    const int tpt = b * NPTS + s * SLICE;          // target point base within its set
    const float* qsrc = (dir == 0) ? x : y;
    const float* tsrc = (dir == 0) ? y : x;

    // ---- A fragments in-register (lane<32 holds k0-7, else k8-15) ----
    half8 afr0, afr1, afr2, afr3;
    {
        const int row = l & 31;
#define MKA(AF, a)                                                                          \
        {                                                                                   \
            const float* p = qsrc + (size_t)(qpt + (wave * 4 + (a)) * 32 + row) * 3;        \
            half8 g0, g1;                                                                   \
            mk_afrag(p[0], p[1], p[2], &g0, &g1);                                           \
            AF = (l < 32) ? g0 : g1;                                                        \
        }
        MKA(afr0, 0) MKA(afr1, 1) MKA(afr2, 2) MKA(afr3, 3)
#undef MKA
    }

    f32x16 mrun0, mrun1, mrun2, mrun3, zc;
#pragma unroll
    for (int r = 0; r < 16; ++r) {
        mrun0[r] = 3.4e38f; mrun1[r] = 3.4e38f;
        mrun2[r] = 3.4e38f; mrun3[r] = 3.4e38f;
        zc[r] = 0.0f;
    }

    // ---- B staging: raw->reg (issue early), pack->ds_write (late) ----
    float2 rA, rB, rC;   // 2 targets (24B) per thread
#define BLOAD(c)                                                                            \
    {                                                                                       \
        const float2* p = (const float2*)(tsrc + (size_t)(tpt + (c) * 512 + tid * 2) * 3);  \
        rA = p[0]; rB = p[1]; rC = p[2];                                                    \
    }
#define BPACK(buf)                                                                          \
    {                                                                                       \
        const int t0 = tid * 2;                                                             \
        const int base = (t0 >> 5) * 1024;                                                  \
        const int r0 = (t0 & 31) * 16;                                                      \
        half8 g0, g1;                                                                       \
        mk_bfrag(rA.x, rA.y, rB.x, &g0, &g1);                                               \
        *(half8*)(&lds[buf][base + r0]) = g0;                                               \
        *(half8*)(&lds[buf][base + 512 + r0]) = g1;                                         \
        mk_bfrag(rB.y, rC.x, rC.y, &g0, &g1);                                               \
        *(half8*)(&lds[buf][base + r0 + 16]) = g0;                                          \
        *(half8*)(&lds[buf][base + 512 + r0 + 16]) = g1;                                    \
    }

#define AGROUP(AF, MR, BB0, BB1)                                                            \
    {                                                                                       \
        f32x16 d0 = __builtin_amdgcn_mfma_f32_32x32x16_f16(AF, BB0, zc, 0, 0, 0);           \
        f32x16 d1 = __builtin_amdgcn_mfma_f32_32x32x16_f16(AF, BB1, zc, 0, 0, 0);           \
        _Pragma("unroll")                                                                   \
        for (int r = 0; r < 16; ++r)                                                        \
            MR[r] = fminf(fminf(MR[r], d0[r]), d1[r]);  /* v_min3 */                        \
    }

#define COMPUTE(BB0, BB1)                                                                   \
    AGROUP(afr0, mrun0, BB0, BB1)                                                           \
    AGROUP(afr1, mrun1, BB0, BB1)                                                           \
    AGROUP(afr2, mrun2, BB0, BB1)                                                           \
    AGROUP(afr3, mrun3, BB0, BB1)

    BLOAD(0)
    BPACK(0)
    __syncthreads();           // buf0 fully written

    int cur = 0;
#pragma unroll 1
    for (int c = 0; c < NCHUNK; ++c) {
        if (c + 1 < NCHUNK) BLOAD(c + 1)   // issue raw loads; latency hides under COMPUTE
        const char* B = lds[cur];
        half8 bA0 = *(const half8*)(B + l * 16);
        half8 bA1 = *(const half8*)(B + 1024 + l * 16);
        half8 bB0, bB1;
#pragma unroll 1
        for (int p = 0; p < 8; p += 2) {
            bB0 = *(const half8*)(B + (p + 1) * 2048 + l * 16);
            bB1 = *(const half8*)(B + (p + 1) * 2048 + 1024 + l * 16);
            COMPUTE(bA0, bA1);
            int pn = (p + 2) & 7;   // wraps on last iter: harmless re-read of pair 0
            bA0 = *(const half8*)(B + pn * 2048 + l * 16);
            bA1 = *(const half8*)(B + pn * 2048 + 1024 + l * 16);
            COMPUTE(bB0, bB1);
        }
        if (c + 1 < NCHUNK) {
            BPACK(cur ^ 1)
            __syncthreads();    // writes visible AND all waves done with lds[cur]
            cur ^= 1;
        }
    }
#undef BLOAD
#undef BPACK
#undef COMPUTE
#undef AGROUP

    // ===== epilogue: column-min via LDS transpose (R8-proven) =====
    // D row = (reg&3) + 8*(reg>>2) + 4*(lane>>5), col = lane&31  [verified R3-R16]
    __syncthreads();            // all waves done reading lds[cur]
    float* ep = (float*)(&lds[0][0]);   // 4 waves * 32 rows * 36 floats = 18432B
    const int hi4 = (l >> 5) * 4;
    const int col = l & 31;

#define EPASS(AA, MR)                                                                       \
    {                                                                                       \
        _Pragma("unroll")                                                                   \
        for (int r = 0; r < 16; ++r) {                                                      \
            int row = (r & 3) + 8 * (r >> 2) + hi4;                                         \
            ep[wave * 1152 + row * 36 + col] = MR[r];                                       \
        }                                                                                   \
    }                                                                                       \
    __syncthreads();                                                                        \
    if (tid < 128) {                                                                        \
        const float4* rp = (const float4*)(ep + (tid >> 5) * 1152 + (tid & 31) * 36);       \
        float4 a01 = f4min(rp[0], rp[1]), a23 = f4min(rp[2], rp[3]);                        \
        float4 a45 = f4min(rp[4], rp[5]), a67 = f4min(rp[6], rp[7]);                        \
        float4 t = f4min(f4min(a01, a23), f4min(a45, a67));                                 \
        float m = fminf(fminf(t.x, t.y), fminf(t.z, t.w));                                  \
        partial[(size_t)s * TOTQ + qbase + (tid >> 5) * 128 + (AA) * 32 + (tid & 31)] = m;  \
    }                                                                                       \
    __syncthreads();

    EPASS(0, mrun0)
    EPASS(1, mrun1)
    EPASS(2, mrun2)
    EPASS(3, mrun3)
#undef EPASS
}

// combine: min over slices + inline ||q||^2 from raw points + sqrt + block tree-sum
__global__ __launch_bounds__(TPB) void combine_mfma_kernel(const float* __restrict__ partial,
                                                           const float* __restrict__ x,
                                                           const float* __restrict__ y,
                                                           float* __restrict__ bsum) {
    int q = blockIdx.x * TPB + threadIdx.x;
    int dir = q >> 15;
    int pidx = q & (BS * NPTS - 1);
    const float* src = (dir == 0) ? x : y;
    float p0 = src[pidx * 3 + 0], p1 = src[pidx * 3 + 1], p2 = src[pidx * 3 + 2];
    float nq = p0 * p0 + p1 * p1 + p2 * p2;   // bitwise == reference pack

    float m = partial[q];
#pragma unroll
    for (int s = 1; s < NS; ++s)
        m = fminf(m, partial[(size_t)s * TOTQ + q]);
    float d = sqrtf(fmaxf(m + nq, 0.0f));
    __shared__ float red[TPB];
    red[threadIdx.x] = d;
    __syncthreads();
    for (int off = TPB / 2; off > 0; off >>= 1) {
        if (threadIdx.x < off) red[threadIdx.x] += red[threadIdx.x + off];
        __syncthreads();
    }
    if (threadIdx.x == 0) bsum[blockIdx.x] = red[0];
}

__global__ __launch_bounds__(TPB) void final_kernel(const float* __restrict__ bsum,
                                                    float* __restrict__ out) {
    __shared__ float red[TPB];
    red[threadIdx.x] = bsum[threadIdx.x];
    __syncthreads();
    for (int off = TPB / 2; off > 0; off >>= 1) {
        if (threadIdx.x < off) red[threadIdx.x] += red[threadIdx.x + off];
        __syncthreads();
    }
    if (threadIdx.x == 0) out[0] = red[0] * (1.0f / 32768.0f);
}

// ================= VALU fallback (round-2 proven) =================
#define QPT 8
#define QPBF (TPB * QPT)
#define NGROUP (TOTQ / QPBF)
#define FNS 8

__global__ __launch_bounds__(TPB) void pack_kernel(const float* __restrict__ x,
                                                   const float* __restrict__ y,
                                                   float4* __restrict__ px,
                                                   float4* __restrict__ py) {
    int i = blockIdx.x * TPB + threadIdx.x;
    if (i < BS * NPTS) {
        float x0 = x[i * 3 + 0], x1 = x[i * 3 + 1], x2 = x[i * 3 + 2];
        px[i] = make_float4(x0, x1, x2, x0 * x0 + x1 * x1 + x2 * x2);
        float y0 = y[i * 3 + 0], y1 = y[i * 3 + 1], y2 = y[i * 3 + 2];
        py[i] = make_float4(y0, y1, y2, y0 * y0 + y1 * y1 + y2 * y2);
    }
}

__global__ __launch_bounds__(TPB) void chamfer_min_kernel(const float4* __restrict__ px,
                                                          const float4* __restrict__ py,
                                                          float* __restrict__ partial) {
    constexpr int SLICEF = NPTS / FNS;
    __shared__ float4 tile[SLICEF];
    const int t = threadIdx.x;
    const int g = blockIdx.x / FNS;
    const int s = blockIdx.x % FNS;
    const int dir = g >> 4;
    const int b = (g >> 2) & 3;
    const int chunk = g & 3;
    const float4* q  = (dir == 0 ? px : py) + b * NPTS + chunk * QPBF;
    const float4* tg = (dir == 0 ? py : px) + b * NPTS + s * SLICEF;
    float a0[QPT], a1[QPT], a2[QPT], qq[QPT], mv[QPT];
#pragma unroll
    for (int i = 0; i < QPT; ++i) {
        float4 v = q[i * TPB + t];
        a0[i] = -2.0f * v.x; a1[i] = -2.0f * v.y; a2[i] = -2.0f * v.z;
        qq[i] = v.w; mv[i] = 3.4e38f;
    }
#pragma unroll
    for (int i = 0; i < SLICEF / TPB; ++i)
        tile[i * TPB + t] = tg[i * TPB + t];
    __syncthreads();
#pragma unroll 2
    for (int j = 0; j < SLICEF; j += 2) {
        float4 v0 = tile[j], v1 = tile[j + 1];
#pragma unroll
        for (int i = 0; i < QPT; ++i) {
            float d0 = fmaf(a2[i], v0.z, fmaf(a1[i], v0.y, fmaf(a0[i], v0.x, v0.w)));
            float d1 = fmaf(a2[i], v1.z, fmaf(a1[i], v1.y, fmaf(a0[i], v1.x, v1.w)));
            mv[i] = fminf(fminf(mv[i], d0), d1);
        }
    }
    const int qg0 = g * QPBF;
#pragma unroll
    for (int i = 0; i < QPT; ++i)
        partial[(size_t)s * TOTQ + qg0 + i * TPB + t] = mv[i] + qq[i];
}

__global__ __launch_bounds__(TPB) void combine_kernel(const float* __restrict__ partial,
                                                      float* __restrict__ bsum) {
    int idx = blockIdx.x * TPB + threadIdx.x;
    float m = 3.4e38f;
#pragma unroll
    for (int s = 0; s < FNS; ++s)
        m = fminf(m, partial[(size_t)s * TOTQ + idx]);
    float d = sqrtf(fmaxf(m, 0.0f));
    __shared__ float red[TPB];
    red[threadIdx.x] = d;
    __syncthreads();
    for (int off = TPB / 2; off > 0; off >>= 1) {
        if (threadIdx.x < off) red[threadIdx.x] += red[threadIdx.x + off];
        __syncthreads();
    }
    if (threadIdx.x == 0) bsum[blockIdx.x] = red[0];
}

// ================= launch =================
extern "C" void kernel_launch(void* const* d_in, const int* in_sizes, int n_in,
                              void* d_out, int out_size, void* d_ws, size_t ws_size,
                              hipStream_t stream) {
    const float* x = (const float*)d_in[0];
    const float* y = (const float*)d_in[1];
    float* out = (float*)d_out;
    char* ws = (char*)d_ws;

    // MFMA-path ws: partial NS*256KB | bsum 1KB
    const size_t off_bs = (size_t)NS * TOTQ * 4;
    const size_t need = off_bs + 1024;

    if (ws_size >= need) {
        float* partial = (float*)ws;
        float* bsum = (float*)(ws + off_bs);
        hipLaunchKernelGGL(mfma_min_kernel, dim3((TOTQ / QPB) * NS), dim3(TPB), 0, stream,
                           x, y, partial);
        hipLaunchKernelGGL(combine_mfma_kernel, dim3(TOTQ / TPB), dim3(TPB), 0, stream,
                           partial, x, y, bsum);
        hipLaunchKernelGGL(final_kernel, dim3(1), dim3(TPB), 0, stream, bsum, out);
    } else {
        float4* px = (float4*)ws;
        float4* py = (float4*)(ws + 512 * 1024);
        float* partial = (float*)(ws + 1024 * 1024);
        float* bsum = (float*)(ws + 1024 * 1024 + (size_t)FNS * TOTQ * 4);
        hipLaunchKernelGGL(pack_kernel, dim3((BS * NPTS + TPB - 1) / TPB), dim3(TPB), 0, stream,
                           x, y, px, py);
        hipLaunchKernelGGL(chamfer_min_kernel, dim3(NGROUP * FNS), dim3(TPB), 0, stream,
                           px, py, partial);
        hipLaunchKernelGGL(combine_kernel, dim3(TOTQ / TPB), dim3(TPB), 0, stream,
                           partial, bsum);
        hipLaunchKernelGGL(final_kernel, dim3(1), dim3(TPB), 0, stream, bsum, out);
    }
}